// Round 14
// baseline (314.748 us; speedup 1.0000x reference)
//
#include <hip/hip_runtime.h>

// ---------------------------------------------------------------------------
// GCN encoder, N=50000, E=1.6M, D=128.
// Round 14: chunk-major feature tables T[c][node][32] (4 x 3.2MB slices) +
// (node,chunk)-parallel agg with chunk as slowest grid dim -> per-XCD L2
// holds the active 3.2MB slice (was 12.8MB thrash, FETCH=13x table).
// Per-edge gather = one 64B line; 4 edge-slots/wave; slot-reduce via shfl.
// GEMMs read/write chunk-major directly (chunk == MFMA ks subtile).
// ---------------------------------------------------------------------------

#define D 128
#define BK_SHIFT 7            // 128 nodes per bucket
#define BK_NODES 128
#define NBMAX 512             // max buckets (N <= 65536)
#define CAP 7936              // slots per bucket (mean ~4092)
#define TILE_A 2048           // edges per block in k_bucketA

typedef __attribute__((ext_vector_type(8))) short bf16x8;
typedef __attribute__((ext_vector_type(4))) float f32x4;

static __device__ __forceinline__ unsigned f2bf(float f) {
  union { float f; unsigned u; } v; v.f = f;
  unsigned r = v.u + 0x7FFF + ((v.u >> 16) & 1);   // round to nearest even
  return r >> 16;
}
static __device__ __forceinline__ float bflo(unsigned u) {
  return __uint_as_float(u << 16);
}
static __device__ __forceinline__ float bfhi(unsigned u) {
  return __uint_as_float(u & 0xFFFF0000u);
}

// ---------------- CSR build (padded packed regions, compact srcSorted) ------

__global__ __launch_bounds__(256) void k_bucketA(const int* __restrict__ src,
                                                 const int* __restrict__ dst,
                                                 int* __restrict__ bcnt,
                                                 int* __restrict__ packed,
                                                 const float* __restrict__ W0,
                                                 const float* __restrict__ W1,
                                                 const float* __restrict__ W2,
                                                 unsigned short* __restrict__ Wb,
                                                 int E, int nb) {
  __shared__ int hist[NBMAX];
  __shared__ int base[NBMAX];
  __shared__ unsigned pv[TILE_A];
  int t = threadIdx.x;
  int e0 = blockIdx.x * TILE_A;

  // piggyback: W -> bf16 (3*16384 elems over first 192 blocks)
  if (blockIdx.x < 192) {
    int i = blockIdx.x * 256 + t;
    const float* W = (i < 16384) ? W0 : (i < 32768 ? W1 : W2);
    Wb[i] = (unsigned short)f2bf(W[i & 16383]);
  }

  for (int b = t; b < nb; b += 256) hist[b] = 0;
  __syncthreads();

  for (int i = t; i < TILE_A; i += 256) {
    int e = e0 + i;
    if (e < E) {
      int d = dst[e];
      int s = src[e];
      unsigned bkt = (unsigned)d >> BK_SHIFT;
      pv[i] = (unsigned)(s & 0xFFFF) | ((unsigned)(d & (BK_NODES - 1)) << 16) |
              (bkt << 23);
      atomicAdd(&hist[bkt], 1);
    }
  }
  __syncthreads();

  for (int b = t; b < nb; b += 256) {
    int h = hist[b];
    if (h) base[b] = atomicAdd(&bcnt[b], h);
  }
  __syncthreads();

  for (int i = t; i < TILE_A; i += 256) {
    int e = e0 + i;
    if (e < E) {
      unsigned v = pv[i];
      unsigned bkt = v >> 23;
      int pos = atomicAdd(&base[bkt], 1);
      if (pos < CAP) packed[(size_t)bkt * CAP + pos] = (int)(v & 0x7FFFFF);
    }
  }
}

// Per bucket: node-level LDS histogram -> rowBeg/rowEnd + dinv + sorted srcs
// (emitted as s<<6 = byte offset of a 64B chunk-slice). Compact global-cursor
// reservation; bucket order in srcSorted irrelevant (explicit row pointers).
__global__ __launch_bounds__(512) void k_bucketB2(const int* __restrict__ packed,
                                                  const int* __restrict__ bcnt,
                                                  int* __restrict__ gcur,
                                                  int* __restrict__ srcSorted,
                                                  int* __restrict__ rowBeg,
                                                  int* __restrict__ rowEnd,
                                                  float* __restrict__ dinv,
                                                  int n) {
  __shared__ int histC[BK_NODES];
  __shared__ int cur[BK_NODES];
  __shared__ int buf[CAP];
  __shared__ int obase;
  int t = threadIdx.x;
  int bkt = blockIdx.x;
  int n0 = bkt << BK_SHIFT;
  int beg = bkt * CAP;
  int cnt = bcnt[bkt];
  if (cnt > CAP) cnt = CAP;

  if (t < BK_NODES) histC[t] = 0;
  __syncthreads();

  for (int i = t; i < cnt; i += 512)
    atomicAdd(&histC[packed[beg + i] >> 16], 1);
  __syncthreads();

  if (t == 0) {
    int run = 0;
#pragma unroll
    for (int j = 0; j < BK_NODES; ++j) { cur[j] = run; run += histC[j]; }
    obase = atomicAdd(gcur, run);
  }
  __syncthreads();

  if (t < BK_NODES && n0 + t < n) {
    int rb = obase + cur[t];
    rowBeg[n0 + t] = rb;
    rowEnd[n0 + t] = rb + histC[t];
    dinv[n0 + t]   = rsqrtf((float)histC[t] + 1.0f);
  }
  __syncthreads();

  for (int i = t; i < cnt; i += 512) {
    int p = packed[beg + i];
    int pos = atomicAdd(&cur[p >> 16], 1);
    buf[pos] = p & 0xFFFF;
  }
  __syncthreads();
  for (int i = t; i < cnt; i += 512)
    srcSorted[obase + i] = buf[i] << 6;           // 64B slice offset
}

// ------------- aggregation (chunked; wave = (node, chunk)) ------------------
// Tables chunk-major: T[c][node][16 u32] (32 bf16 cols). srcSorted = s<<6.
// Wave lanes: es = lane>>4 (edge slot 0..3), sl = lane&15 (col-pair).
// ox = dinv[d]*(T[c][d] + sum_e T[c][src_e]).
// EPI=1: h=relu((ox+bias)*mask); out = bf16(dinv*h).  EPI=2: out = bf16(ox).

template <int EPI>
__global__ __launch_bounds__(256) void k_aggc(const unsigned* __restrict__ T,
                                              const int* __restrict__ srcSorted,
                                              const int* __restrict__ rowBeg,
                                              const int* __restrict__ rowEnd,
                                              const float* __restrict__ dinv,
                                              const float* __restrict__ bias,
                                              const float* __restrict__ mask,
                                              unsigned* __restrict__ outB,
                                              int n, int nodeBlk) {
  int c    = blockIdx.x / nodeBlk;              // chunk: slowest-varying
  int nblk = blockIdx.x - c * nodeBlk;
  int node = nblk * 4 + (threadIdx.x >> 6);
  if (node >= n) return;
  int lane = threadIdx.x & 63;
  int es   = lane >> 4;
  int sl   = lane & 15;

  const char* Tb = (const char*)T + (size_t)c * n * 64;  // this chunk's slice
  int slb = sl << 2;

  int beg = rowBeg[node], end = rowEnd[node];
  float ax = 0.f, ay = 0.f, bx = 0.f, by = 0.f;
  int j = beg;
  for (; j + 15 < end; j += 16) {
    int o0 = srcSorted[j + es];
    int o1 = srcSorted[j + 4 + es];
    int o2 = srcSorted[j + 8 + es];
    int o3 = srcSorted[j + 12 + es];
    unsigned u0 = *(const unsigned*)(Tb + o0 + slb);
    unsigned u1 = *(const unsigned*)(Tb + o1 + slb);
    unsigned u2 = *(const unsigned*)(Tb + o2 + slb);
    unsigned u3 = *(const unsigned*)(Tb + o3 + slb);
    ax += bflo(u0) + bflo(u2);  ay += bfhi(u0) + bfhi(u2);
    bx += bflo(u1) + bflo(u3);  by += bfhi(u1) + bfhi(u3);
  }
  for (; j + 3 < end; j += 4) {
    int o = srcSorted[j + es];
    unsigned u = *(const unsigned*)(Tb + o + slb);
    ax += bflo(u);
    ay += bfhi(u);
  }
  if (j + es < end) {                            // tail 0..3 edges
    int o = srcSorted[j + es];
    unsigned u = *(const unsigned*)(Tb + o + slb);
    ax += bflo(u);
    ay += bfhi(u);
  }
  if (es == 0) {                                 // self term (slot 0)
    unsigned u = *(const unsigned*)(Tb + (node << 6) + slb);
    ax += bflo(u);
    ay += bfhi(u);
  }
  float sx = ax + bx, sy = ay + by;
  sx += __shfl_xor(sx, 16);  sy += __shfl_xor(sy, 16);
  sx += __shfl_xor(sx, 32);  sy += __shfl_xor(sy, 32);

  float dn = dinv[node];
  float ox = sx * dn;
  float oy = sy * dn;
  unsigned w;
  if (EPI == 1) {
    float2 bv = ((const float2*)bias)[c * 16 + sl];
    float2 mv = ((const float2*)mask)[(size_t)node * 64 + c * 16 + sl];
    float hx = fmaxf((ox + bv.x) * mv.x, 0.f);
    float hy = fmaxf((oy + bv.y) * mv.y, 0.f);
    w = f2bf(hx * dn) | (f2bf(hy * dn) << 16);
  } else {
    w = f2bf(ox) | (f2bf(oy) << 16);
  }
  if (lane < 16)
    outB[((size_t)c * n + node) * 16 + sl] = w;
}

// ------------- MFMA GEMM 0: h0 = bf16(dinv * (x @ W0^T)), chunk-major out ---
// Wave computes 16 rows x 128 cols. A frag: row=lane&15, k=(lane>>4)*8+j
// (f32 row-major x, cast inline). B frag: col=lane&15 over W[col][k].
// C/D: col=lane&15, row=(lane>>4)*4+reg. Output scalar u16 at chunk-major.

__global__ __launch_bounds__(256) void k_gemm0(const float* __restrict__ X,
                                               const unsigned short* __restrict__ Wb,
                                               const float* __restrict__ prescale,
                                               unsigned short* __restrict__ Cb,
                                               int nrows) {
  int wid  = threadIdx.x >> 6;
  int lane = threadIdx.x & 63;
  int r0   = blockIdx.x * 64 + wid * 16;
  int arow = r0 + (lane & 15);
  int kb   = (lane >> 4) * 8;
  bool rowok = arow < nrows;

  bf16x8 a[4];
#pragma unroll
  for (int ks = 0; ks < 4; ++ks) {
    bf16x8 t;
    if (rowok) {
      const float* p = X + (size_t)arow * D + ks * 32 + kb;
      float4 f0 = *(const float4*)(p);
      float4 f1 = *(const float4*)(p + 4);
      t[0] = (short)f2bf(f0.x); t[1] = (short)f2bf(f0.y);
      t[2] = (short)f2bf(f0.z); t[3] = (short)f2bf(f0.w);
      t[4] = (short)f2bf(f1.x); t[5] = (short)f2bf(f1.y);
      t[6] = (short)f2bf(f1.z); t[7] = (short)f2bf(f1.w);
    } else {
      for (int q = 0; q < 8; ++q) t[q] = 0;
    }
    a[ks] = t;
  }

  int rbase = r0 + (lane >> 4) * 4;
  float sc[4];
#pragma unroll
  for (int reg = 0; reg < 4; ++reg) {
    int rr = rbase + reg;
    sc[reg] = (rr < nrows) ? prescale[rr] : 1.0f;
  }

#pragma unroll
  for (int ct = 0; ct < 8; ++ct) {
    int col = ct * 16 + (lane & 15);
    f32x4 acc = {0.f, 0.f, 0.f, 0.f};
#pragma unroll
    for (int ks = 0; ks < 4; ++ks) {
      bf16x8 b = *reinterpret_cast<const bf16x8*>(Wb + (size_t)col * D + ks * 32 + kb);
      acc = __builtin_amdgcn_mfma_f32_16x16x32_bf16(a[ks], b, acc, 0, 0, 0);
    }
    int cch = col >> 5, cin = col & 31;
#pragma unroll
    for (int reg = 0; reg < 4; ++reg) {
      int rr = rbase + reg;
      if (rr < nrows)
        Cb[((size_t)cch * nrows + rr) * 32 + cin] =
            (unsigned short)f2bf(acc[reg] * sc[reg]);
    }
  }
}

// Fused dual GEMM: C1 = X@W1^T + b1, C2 = X@W2^T + b2; X chunk-major bf16.
__global__ __launch_bounds__(256) void k_gemm_mfma2(const unsigned short* __restrict__ X,
                                                    const unsigned short* __restrict__ W1b,
                                                    const unsigned short* __restrict__ W2b,
                                                    const float* __restrict__ b1,
                                                    const float* __restrict__ b2,
                                                    float* __restrict__ C1,
                                                    float* __restrict__ C2,
                                                    int nrows) {
  int wid  = threadIdx.x >> 6;
  int lane = threadIdx.x & 63;
  int r0   = blockIdx.x * 64 + wid * 16;
  int arow = r0 + (lane & 15);
  int kb   = (lane >> 4) * 8;
  bool rowok = arow < nrows;

  bf16x8 a[4];
#pragma unroll
  for (int ks = 0; ks < 4; ++ks) {
    bf16x8 t;
    if (rowok)
      t = *reinterpret_cast<const bf16x8*>(X + ((size_t)ks * nrows + arow) * 32 + kb);
    else { for (int q = 0; q < 8; ++q) t[q] = 0; }
    a[ks] = t;
  }

  int rbase = r0 + (lane >> 4) * 4;

#pragma unroll
  for (int wm = 0; wm < 2; ++wm) {
    const unsigned short* Wb = (wm == 0) ? W1b : W2b;
    const float* bias        = (wm == 0) ? b1 : b2;
    float* Cf                = (wm == 0) ? C1 : C2;
#pragma unroll
    for (int ct = 0; ct < 8; ++ct) {
      int col = ct * 16 + (lane & 15);
      f32x4 acc = {0.f, 0.f, 0.f, 0.f};
#pragma unroll
      for (int ks = 0; ks < 4; ++ks) {
        bf16x8 b = *reinterpret_cast<const bf16x8*>(Wb + (size_t)col * D + ks * 32 + kb);
        acc = __builtin_amdgcn_mfma_f32_16x16x32_bf16(a[ks], b, acc, 0, 0, 0);
      }
      float bc = bias[col];
#pragma unroll
      for (int reg = 0; reg < 4; ++reg) {
        int rr = rbase + reg;
        if (rr < nrows) Cf[(size_t)rr * D + col] = acc[reg] + bc;
      }
    }
  }
}

// ---------------- fallback path (atomic, all f32) ----------------

__global__ __launch_bounds__(256) void k_deg_f(const int* __restrict__ dst,
                                               float* __restrict__ deg, int E) {
  int i = blockIdx.x * 256 + threadIdx.x;
  if (i < E) atomicAdd(&deg[dst[i]], 1.0f);
}

__global__ __launch_bounds__(256) void k_dinv_f(float* __restrict__ deg, int n) {
  int i = blockIdx.x * 256 + threadIdx.x;
  if (i < n) deg[i] = rsqrtf(deg[i] + 1.0f);
}

__global__ __launch_bounds__(256) void k_selfmul(const float* __restrict__ X,
                                                 const float* __restrict__ dinv,
                                                 float* __restrict__ out, int n) {
  int i = blockIdx.x * 256 + threadIdx.x;
  if (i >= n * 32) return;
  int r = i >> 5, c4 = (i & 31) << 2;
  float di = dinv[r];
  float s = di * di;
  float4 h = *(const float4*)(X + (size_t)r * D + c4);
  h.x *= s; h.y *= s; h.z *= s; h.w *= s;
  *(float4*)(out + (size_t)r * D + c4) = h;
}

__global__ __launch_bounds__(256) void k_relumask(float* __restrict__ h,
                                                  const float* __restrict__ mask, int n) {
  int i = blockIdx.x * 256 + threadIdx.x;
  if (i >= n * 32) return;
  float4 v = *(const float4*)(h + (size_t)i * 4);
  float4 m = *(const float4*)(mask + (size_t)i * 4);
  v.x = fmaxf(v.x * m.x, 0.f);
  v.y = fmaxf(v.y * m.y, 0.f);
  v.z = fmaxf(v.z * m.z, 0.f);
  v.w = fmaxf(v.w * m.w, 0.f);
  *(float4*)(h + (size_t)i * 4) = v;
}

__global__ __launch_bounds__(256) void k_aggatomic(const float* __restrict__ X,
                                                   const int* __restrict__ src,
                                                   const int* __restrict__ dst,
                                                   const float* __restrict__ dinv,
                                                   float* __restrict__ out, int E) {
  int gid = blockIdx.x * 256 + threadIdx.x;
  int wave = gid >> 6;
  int lane = threadIdx.x & 63;
  int nw = (gridDim.x * 256) >> 6;
  for (int e = wave; e < E; e += nw) {
    int s = src[e], d = dst[e];
    float nrm = dinv[s] * dinv[d];
    float2 v = ((const float2*)(X + (size_t)s * D))[lane];
    float* op = out + (size_t)d * D + lane * 2;
    atomicAdd(op, v.x * nrm);
    atomicAdd(op + 1, v.y * nrm);
  }
}

__global__ __launch_bounds__(256) void k_addbias(float* __restrict__ C,
                                                 const float* __restrict__ bias, int n) {
  int i = blockIdx.x * 256 + threadIdx.x;
  if (i >= n * 32) return;
  int c4 = (i & 31) << 2;
  float4 v = *(const float4*)(C + (size_t)i * 4);
  float4 b = *(const float4*)(bias + c4);
  v.x += b.x; v.y += b.y; v.z += b.z; v.w += b.w;
  *(float4*)(C + (size_t)i * 4) = v;
}

__global__ __launch_bounds__(256) void k_gemm128(const float* __restrict__ X,
                                                 const float* __restrict__ W,
                                                 const float* __restrict__ bias,
                                                 float* __restrict__ Cf,
                                                 int nrows) {
  __shared__ float Xs[64][132];
  __shared__ float Ws[32][128];

  int tid = threadIdx.x;
  int row0 = blockIdx.x * 64;

  for (int t = tid; t < 2048; t += 256) {
    int r = t >> 5;
    int c4 = (t & 31) << 2;
    int gr = row0 + r;
    float4 v = make_float4(0.f, 0.f, 0.f, 0.f);
    if (gr < nrows) v = *(const float4*)(X + (size_t)gr * D + c4);
    Xs[r][c4 + 0] = v.x; Xs[r][c4 + 1] = v.y;
    Xs[r][c4 + 2] = v.z; Xs[r][c4 + 3] = v.w;
  }

  float acc[4][8];
#pragma unroll
  for (int i = 0; i < 4; ++i)
#pragma unroll
    for (int j = 0; j < 8; ++j) acc[i][j] = 0.f;

  int ty = tid >> 4, tx = tid & 15;
  int r0 = ty << 2, c0 = tx << 3;

  for (int k0 = 0; k0 < 128; k0 += 32) {
    int j = tid >> 1;
    int kkb = (tid & 1) << 4;
    const float4* wp = (const float4*)(W + j * D + k0 + kkb);
    float4 wa = wp[0], wb = wp[1], wc = wp[2], wd = wp[3];

    __syncthreads();
    Ws[kkb +  0][j] = wa.x; Ws[kkb +  1][j] = wa.y; Ws[kkb +  2][j] = wa.z; Ws[kkb +  3][j] = wa.w;
    Ws[kkb +  4][j] = wb.x; Ws[kkb +  5][j] = wb.y; Ws[kkb +  6][j] = wb.z; Ws[kkb +  7][j] = wb.w;
    Ws[kkb +  8][j] = wc.x; Ws[kkb +  9][j] = wc.y; Ws[kkb + 10][j] = wc.z; Ws[kkb + 11][j] = wc.w;
    Ws[kkb + 12][j] = wd.x; Ws[kkb + 13][j] = wd.y; Ws[kkb + 14][j] = wd.z; Ws[kkb + 15][j] = wd.w;
    __syncthreads();

#pragma unroll
    for (int kk = 0; kk < 32; ++kk) {
      float xi[4];
      xi[0] = Xs[r0 + 0][k0 + kk];
      xi[1] = Xs[r0 + 1][k0 + kk];
      xi[2] = Xs[r0 + 2][k0 + kk];
      xi[3] = Xs[r0 + 3][k0 + kk];
      float4 wv0 = *(const float4*)(&Ws[kk][c0]);
      float4 wv1 = *(const float4*)(&Ws[kk][c0 + 4]);
      float wf[8] = {wv0.x, wv0.y, wv0.z, wv0.w, wv1.x, wv1.y, wv1.z, wv1.w};
#pragma unroll
      for (int i = 0; i < 4; ++i)
#pragma unroll
        for (int jj = 0; jj < 8; ++jj) acc[i][jj] += xi[i] * wf[jj];
    }
  }

  float4 bv0 = make_float4(0.f, 0.f, 0.f, 0.f);
  float4 bv1 = make_float4(0.f, 0.f, 0.f, 0.f);
  if (bias) {
    bv0 = *(const float4*)(bias + c0);
    bv1 = *(const float4*)(bias + c0 + 4);
  }

#pragma unroll
  for (int i = 0; i < 4; ++i) {
    int gr = row0 + r0 + i;
    if (gr < nrows) {
      *(float4*)(Cf + (size_t)gr * D + c0) =
          make_float4(acc[i][0] + bv0.x, acc[i][1] + bv0.y,
                      acc[i][2] + bv0.z, acc[i][3] + bv0.w);
      *(float4*)(Cf + (size_t)gr * D + c0 + 4) =
          make_float4(acc[i][4] + bv1.x, acc[i][5] + bv1.y,
                      acc[i][6] + bv1.z, acc[i][7] + bv1.w);
    }
  }
}

// ---------------- launch ----------------

extern "C" void kernel_launch(void* const* d_in, const int* in_sizes, int n_in,
                              void* d_out, int out_size, void* d_ws, size_t ws_size,
                              hipStream_t stream) {
  const float* x    = (const float*)d_in[0];
  const int*   ei   = (const int*)d_in[1];
  const float* mask = (const float*)d_in[2];
  const float* W0   = (const float*)d_in[3];
  const float* b0   = (const float*)d_in[4];
  const float* W1   = (const float*)d_in[5];
  const float* b1   = (const float*)d_in[6];
  const float* W2   = (const float*)d_in[7];
  const float* b2   = (const float*)d_in[8];

  const int N = in_sizes[0] / D;
  const int E = in_sizes[1] / 2;
  const int* srcv = ei;
  const int* dstv = ei + E;

  float* out  = (float*)d_out;
  float* outA = out;                    // x_
  float* outB = out + (size_t)N * D;    // x2

  const size_t featBytes  = (size_t)N * D * sizeof(float);
  const size_t featBytesH = (size_t)N * D * sizeof(short);
  const int gGemm  = (N + 63) / 64;
  const int gEdge  = (E + 255) / 256;
  const int gNode  = (N + 255) / 256;
  const int gElem  = (N * 32 + 255) / 256;
  const int nb     = (N + BK_NODES - 1) >> BK_SHIFT;
  const int gBA    = (E + TILE_A - 1) / TILE_A;
  const int nodeBlk = (N + 3) / 4;
  const int gAgg   = nodeBlk * 4;                // chunk-major grid
  const size_t padBytes = (size_t)nb * CAP * 4;  // packed (aliases gbf)

  auto align256 = [](size_t v) { return (v + 255) & ~(size_t)255; };
  char* w = (char*)d_ws;
  size_t off = 0;
  int*   bcnt      = (int*)(w + off);   off = align256(off + (NBMAX + 1) * 4);
  int*   gcur      = bcnt + NBMAX;
  int*   rowBeg    = (int*)(w + off);   off = align256(off + (size_t)N * 4);
  int*   rowEnd    = (int*)(w + off);   off = align256(off + (size_t)N * 4);
  float* dinv      = (float*)(w + off); off = align256(off + (size_t)N * 4);
  int*   srcSorted = (int*)(w + off);   off = align256(off + (size_t)E * 4);
  unsigned short* Wb = (unsigned short*)(w + off); off = align256(off + 3 * 16384 * 2);
  unsigned* h0bf   = (unsigned*)(w + off); off = align256(off + featBytesH);
  unsigned* hbf    = (unsigned*)(w + off); off = align256(off + featBytesH);
  unsigned* gbf    = (unsigned*)(w + off);
  size_t offA = off + featBytesH;
  size_t offB = off + padBytes;
  off = align256(offA > offB ? offA : offB);
  int*   packed    = (int*)gbf;         // aliases gbf (consumed before written)
  size_t need = off;

  if (ws_size >= need && N <= 65536 && nb <= NBMAX &&
      (E / nb) + 1024 <= CAP) {
    // ---- CSR build (2 kernels + tiny memset); bucketA also converts W ----
    hipMemsetAsync(bcnt, 0, (size_t)(NBMAX + 1) * sizeof(int), stream);
    k_bucketA<<<gBA, 256, 0, stream>>>(srcv, dstv, bcnt, packed,
                                       W0, W1, W2, Wb, E, nb);
    k_bucketB2<<<nb, 512, 0, stream>>>(packed, bcnt, gcur, srcSorted,
                                       rowBeg, rowEnd, dinv, N);

    // t0 = bf16(dinv * (x @ W0^T))   (chunk-major)
    k_gemm0<<<gGemm, 256, 0, stream>>>(x, Wb, dinv, (unsigned short*)h0bf, N);
    // t1 = bf16(dinv * relu((agg + b0) * mask))   (chunk-major)
    k_aggc<1><<<gAgg, 256, 0, stream>>>(h0bf, srcSorted, rowBeg, rowEnd,
                                        dinv, b0, mask, hbf, N, nodeBlk);
    // g = bf16(agg)   (chunk-major)
    k_aggc<2><<<gAgg, 256, 0, stream>>>(hbf, srcSorted, rowBeg, rowEnd,
                                        dinv, nullptr, nullptr, gbf, N, nodeBlk);
    // x_ = g @ W1^T + b1 ; x2 = g @ W2^T + b2 (fused)
    k_gemm_mfma2<<<gGemm, 256, 0, stream>>>(
        (const unsigned short*)gbf, Wb + 16384, Wb + 32768, b1, b2,
        outA, outB, N);
  } else {
    // ---- atomic fallback (commuted, 2 aggs, all f32) ----
    float* fdinv = (float*)(w);
    float* fA    = (float*)(w + 0x40000);
    float* fB    = (float*)((char*)fA + featBytes);
    hipMemsetAsync(fdinv, 0, (size_t)N * sizeof(float), stream);
    k_deg_f<<<gEdge, 256, 0, stream>>>(dstv, fdinv, E);
    k_dinv_f<<<gNode, 256, 0, stream>>>(fdinv, N);
    k_gemm128<<<gGemm, 256, 0, stream>>>(x, W0, nullptr, fB, N);
    k_selfmul<<<gElem, 256, 0, stream>>>(fB, fdinv, fA, N);
    k_aggatomic<<<4096, 256, 0, stream>>>(fB, srcv, dstv, fdinv, fA, E);
    k_addbias<<<gElem, 256, 0, stream>>>(fA, b0, N);
    k_relumask<<<gElem, 256, 0, stream>>>(fA, mask, N);
    k_selfmul<<<gElem, 256, 0, stream>>>(fA, fdinv, fB, N);
    k_aggatomic<<<4096, 256, 0, stream>>>(fA, srcv, dstv, fdinv, fB, E);
    k_gemm128<<<gGemm, 256, 0, stream>>>(fB, W1, b1, outA, N);
    k_gemm128<<<gGemm, 256, 0, stream>>>(fB, W2, b2, outB, N);
  }
}

// Round 15
// 214.370 us; speedup vs baseline: 1.4682x; 1.4682x over previous
//
#include <hip/hip_runtime.h>

// ---------------------------------------------------------------------------
// GCN encoder, N=50000, E=1.6M, D=128.
// Round 15: revert round-14 chunked agg (latency-bound regression: 4-deep MLP,
// 0.8 TB/s miss BW). Back to round-13 row-major agg (63us, ~6.5 TB/s
// delivered). One change: k_bucketA at 512 threads / TILE_A=4096.
// ---------------------------------------------------------------------------

#define D 128
#define BK_SHIFT 7            // 128 nodes per bucket
#define BK_NODES 128
#define NBMAX 512             // max buckets (N <= 65536)
#define CAP 7936              // slots per bucket (mean ~4092)
#define TILE_A 4096           // edges per block in k_bucketA (512 threads)

typedef __attribute__((ext_vector_type(8))) short bf16x8;
typedef __attribute__((ext_vector_type(4))) float f32x4;

static __device__ __forceinline__ unsigned f2bf(float f) {
  union { float f; unsigned u; } v; v.f = f;
  unsigned r = v.u + 0x7FFF + ((v.u >> 16) & 1);   // round to nearest even
  return r >> 16;
}
static __device__ __forceinline__ float bflo(unsigned u) {
  return __uint_as_float(u << 16);
}
static __device__ __forceinline__ float bfhi(unsigned u) {
  return __uint_as_float(u & 0xFFFF0000u);
}

// ---------------- CSR build (padded packed regions, compact srcSorted) ------

// Single pass: LDS-batched per-bucket counts, direct global reservation,
// write packed (src | dstoff<<16 | bkt<<23) into bucket region bkt*CAP.
// First 96 blocks also convert W0|W1|W2 (f32) -> Wb (bf16), 512 elems each.
__global__ __launch_bounds__(512) void k_bucketA(const int* __restrict__ src,
                                                 const int* __restrict__ dst,
                                                 int* __restrict__ bcnt,
                                                 int* __restrict__ packed,
                                                 const float* __restrict__ W0,
                                                 const float* __restrict__ W1,
                                                 const float* __restrict__ W2,
                                                 unsigned short* __restrict__ Wb,
                                                 int E, int nb) {
  __shared__ int hist[NBMAX];
  __shared__ int base[NBMAX];
  __shared__ unsigned pv[TILE_A];
  int t = threadIdx.x;
  int e0 = blockIdx.x * TILE_A;

  // piggyback: W -> bf16 (3*16384 elems over first 96 blocks x 512 threads)
  if (blockIdx.x < 96) {
    int i = blockIdx.x * 512 + t;
    const float* W = (i < 16384) ? W0 : (i < 32768 ? W1 : W2);
    Wb[i] = (unsigned short)f2bf(W[i & 16383]);
  }

  for (int b = t; b < nb; b += 512) hist[b] = 0;
  __syncthreads();

  for (int i = t; i < TILE_A; i += 512) {
    int e = e0 + i;
    if (e < E) {
      int d = dst[e];
      int s = src[e];
      unsigned bkt = (unsigned)d >> BK_SHIFT;
      pv[i] = (unsigned)(s & 0xFFFF) | ((unsigned)(d & (BK_NODES - 1)) << 16) |
              (bkt << 23);
      atomicAdd(&hist[bkt], 1);
    }
  }
  __syncthreads();

  for (int b = t; b < nb; b += 512) {
    int h = hist[b];
    if (h) base[b] = atomicAdd(&bcnt[b], h);
  }
  __syncthreads();

  for (int i = t; i < TILE_A; i += 512) {
    int e = e0 + i;
    if (e < E) {
      unsigned v = pv[i];
      unsigned bkt = v >> 23;
      int pos = atomicAdd(&base[bkt], 1);
      if (pos < CAP) packed[(size_t)bkt * CAP + pos] = (int)(v & 0x7FFFFF);
    }
  }
}

// Per bucket: node-level LDS histogram -> rowBeg/rowEnd + dinv + sorted srcs
// (BYTE OFFSETS s<<8). srcSorted written COMPACTLY at a region reserved from
// a global cursor (bucket order in srcSorted is irrelevant: rowBeg/rowEnd
// are explicit per-node pointers).
__global__ __launch_bounds__(512) void k_bucketB2(const int* __restrict__ packed,
                                                  const int* __restrict__ bcnt,
                                                  int* __restrict__ gcur,
                                                  int* __restrict__ srcSorted,
                                                  int* __restrict__ rowBeg,
                                                  int* __restrict__ rowEnd,
                                                  float* __restrict__ dinv,
                                                  int n) {
  __shared__ int histC[BK_NODES];
  __shared__ int cur[BK_NODES];
  __shared__ int buf[CAP];
  __shared__ int obase;
  int t = threadIdx.x;
  int bkt = blockIdx.x;
  int n0 = bkt << BK_SHIFT;
  int beg = bkt * CAP;
  int cnt = bcnt[bkt];
  if (cnt > CAP) cnt = CAP;

  if (t < BK_NODES) histC[t] = 0;
  __syncthreads();

  for (int i = t; i < cnt; i += 512)
    atomicAdd(&histC[packed[beg + i] >> 16], 1);
  __syncthreads();

  if (t == 0) {
    int run = 0;
#pragma unroll
    for (int j = 0; j < BK_NODES; ++j) { cur[j] = run; run += histC[j]; }
    obase = atomicAdd(gcur, run);   // compact reservation
  }
  __syncthreads();

  if (t < BK_NODES && n0 + t < n) {
    int rb = obase + cur[t];
    rowBeg[n0 + t] = rb;
    rowEnd[n0 + t] = rb + histC[t];
    dinv[n0 + t]   = rsqrtf((float)histC[t] + 1.0f);
  }
  __syncthreads();   // rowBeg writes read cur before scatter mutates it

  for (int i = t; i < cnt; i += 512) {
    int p = packed[beg + i];
    int pos = atomicAdd(&cur[p >> 16], 1);
    buf[pos] = p & 0xFFFF;
  }
  __syncthreads();
  for (int i = t; i < cnt; i += 512)
    srcSorted[obase + i] = buf[i] << 8;           // byte offset, compact
}

// ------------- aggregation (wave/node; pre-scaled bf16 table) ---------------
// T[s] = bf16(dinv[s]*h[s]) packed 2/word; srcSorted holds byte offsets s<<8.
// ox = dinv[d]*(T[d] + sum T[s]).
// EPI=1: h=relu((ox+bias)*mask); outB = bf16(dinv*h).  EPI=2: outB = bf16(ox).

template <int EPI>
__global__ __launch_bounds__(256) void k_aggb(const unsigned* __restrict__ T,
                                              const int* __restrict__ srcSorted,
                                              const int* __restrict__ rowBeg,
                                              const int* __restrict__ rowEnd,
                                              const float* __restrict__ dinv,
                                              const float* __restrict__ bias,
                                              const float* __restrict__ mask,
                                              unsigned* __restrict__ outB,
                                              int n) {
  int wave = (blockIdx.x * 256 + threadIdx.x) >> 6;
  int lane = threadIdx.x & 63;
  if (wave >= n) return;
  const char* Tb = (const char*)T;
  int lo = lane << 2;
  int beg = rowBeg[wave], end = rowEnd[wave];
  float a0x = 0.f, a0y = 0.f, a1x = 0.f, a1y = 0.f;
  float a2x = 0.f, a2y = 0.f, a3x = 0.f, a3y = 0.f;
  int j = beg;
  for (; j + 15 < end; j += 16) {
    unsigned u[16];
#pragma unroll
    for (int q = 0; q < 16; ++q)
      u[q] = *(const unsigned*)(Tb + srcSorted[j + q] + lo);
#pragma unroll
    for (int q = 0; q < 16; q += 4) {
      a0x += bflo(u[q + 0]);  a0y += bfhi(u[q + 0]);
      a1x += bflo(u[q + 1]);  a1y += bfhi(u[q + 1]);
      a2x += bflo(u[q + 2]);  a2y += bfhi(u[q + 2]);
      a3x += bflo(u[q + 3]);  a3y += bfhi(u[q + 3]);
    }
  }
  for (; j + 7 < end; j += 8) {
    unsigned u[8];
#pragma unroll
    for (int q = 0; q < 8; ++q)
      u[q] = *(const unsigned*)(Tb + srcSorted[j + q] + lo);
#pragma unroll
    for (int q = 0; q < 8; q += 4) {
      a0x += bflo(u[q + 0]);  a0y += bfhi(u[q + 0]);
      a1x += bflo(u[q + 1]);  a1y += bfhi(u[q + 1]);
      a2x += bflo(u[q + 2]);  a2y += bfhi(u[q + 2]);
      a3x += bflo(u[q + 3]);  a3y += bfhi(u[q + 3]);
    }
  }
  for (; j < end; ++j) {
    unsigned u = *(const unsigned*)(Tb + srcSorted[j] + lo);
    a0x += bflo(u);
    a0y += bfhi(u);
  }
  unsigned us = T[(size_t)wave * 64 + lane];   // self term
  float dn = dinv[wave];
  float ox = ((a0x + a1x) + (a2x + a3x) + bflo(us)) * dn;
  float oy = ((a0y + a1y) + (a2y + a3y) + bfhi(us)) * dn;
  if (EPI == 1) {
    float2 bv = ((const float2*)bias)[lane];
    float2 mv = ((const float2*)mask)[(size_t)wave * 64 + lane];
    float hx = fmaxf((ox + bv.x) * mv.x, 0.f);
    float hy = fmaxf((oy + bv.y) * mv.y, 0.f);
    outB[(size_t)wave * 64 + lane] = f2bf(hx * dn) | (f2bf(hy * dn) << 16);
  } else {
    outB[(size_t)wave * 64 + lane] = f2bf(ox) | (f2bf(oy) << 16);
  }
}

// ------------- MFMA GEMM: C = X @ W^T, 16x16x32 bf16, no LDS ---------------
// Wave computes 16 rows x 128 cols. A frag: row=lane&15, k=(lane>>4)*8+j.
// B frag: col=lane&15, same k over W[col][k]. C/D: col=lane&15,
// row=(lane>>4)*4+reg.

template <bool BF16IN, bool BF16OUT>
__global__ __launch_bounds__(256) void k_gemm_mfma(const void* __restrict__ Xv,
                                                   const unsigned short* __restrict__ Wb,
                                                   const float* __restrict__ bias,
                                                   const float* __restrict__ prescale,
                                                   float* __restrict__ Cf,
                                                   unsigned short* __restrict__ Cb,
                                                   int nrows) {
  int wid  = threadIdx.x >> 6;
  int lane = threadIdx.x & 63;
  int r0   = blockIdx.x * 64 + wid * 16;
  int arow = r0 + (lane & 15);
  int kb   = (lane >> 4) * 8;
  bool rowok = arow < nrows;

  bf16x8 a[4];
  if (BF16IN) {
    const unsigned short* X = (const unsigned short*)Xv;
#pragma unroll
    for (int ks = 0; ks < 4; ++ks) {
      bf16x8 t;
      if (rowok) t = *reinterpret_cast<const bf16x8*>(X + (size_t)arow * D + ks * 32 + kb);
      else { for (int q = 0; q < 8; ++q) t[q] = 0; }
      a[ks] = t;
    }
  } else {
    const float* X = (const float*)Xv;
#pragma unroll
    for (int ks = 0; ks < 4; ++ks) {
      bf16x8 t;
      if (rowok) {
        const float* p = X + (size_t)arow * D + ks * 32 + kb;
        float4 f0 = *(const float4*)(p);
        float4 f1 = *(const float4*)(p + 4);
        t[0] = (short)f2bf(f0.x); t[1] = (short)f2bf(f0.y);
        t[2] = (short)f2bf(f0.z); t[3] = (short)f2bf(f0.w);
        t[4] = (short)f2bf(f1.x); t[5] = (short)f2bf(f1.y);
        t[6] = (short)f2bf(f1.z); t[7] = (short)f2bf(f1.w);
      } else {
        for (int q = 0; q < 8; ++q) t[q] = 0;
      }
      a[ks] = t;
    }
  }

  int rbase = r0 + (lane >> 4) * 4;
  float sc[4];
  if (BF16OUT) {
#pragma unroll
    for (int reg = 0; reg < 4; ++reg) {
      int rr = rbase + reg;
      sc[reg] = (prescale && rr < nrows) ? prescale[rr] : 1.0f;
    }
  }

#pragma unroll
  for (int ct = 0; ct < 8; ++ct) {
    int col = ct * 16 + (lane & 15);
    f32x4 acc = {0.f, 0.f, 0.f, 0.f};
#pragma unroll
    for (int ks = 0; ks < 4; ++ks) {
      bf16x8 b = *reinterpret_cast<const bf16x8*>(Wb + (size_t)col * D + ks * 32 + kb);
      acc = __builtin_amdgcn_mfma_f32_16x16x32_bf16(a[ks], b, acc, 0, 0, 0);
    }
    if (BF16OUT) {
#pragma unroll
      for (int reg = 0; reg < 4; ++reg) {
        int rr = rbase + reg;
        if (rr < nrows)
          Cb[(size_t)rr * D + col] = (unsigned short)f2bf(acc[reg] * sc[reg]);
      }
    } else {
      float bc = bias ? bias[col] : 0.f;
#pragma unroll
      for (int reg = 0; reg < 4; ++reg) {
        int rr = rbase + reg;
        if (rr < nrows) Cf[(size_t)rr * D + col] = acc[reg] + bc;
      }
    }
  }
}

// Fused dual GEMM: C1 = X@W1^T + b1, C2 = X@W2^T + b2 (bf16 in, f32 out).
__global__ __launch_bounds__(256) void k_gemm_mfma2(const unsigned short* __restrict__ X,
                                                    const unsigned short* __restrict__ W1b,
                                                    const unsigned short* __restrict__ W2b,
                                                    const float* __restrict__ b1,
                                                    const float* __restrict__ b2,
                                                    float* __restrict__ C1,
                                                    float* __restrict__ C2,
                                                    int nrows) {
  int wid  = threadIdx.x >> 6;
  int lane = threadIdx.x & 63;
  int r0   = blockIdx.x * 64 + wid * 16;
  int arow = r0 + (lane & 15);
  int kb   = (lane >> 4) * 8;
  bool rowok = arow < nrows;

  bf16x8 a[4];
#pragma unroll
  for (int ks = 0; ks < 4; ++ks) {
    bf16x8 t;
    if (rowok) t = *reinterpret_cast<const bf16x8*>(X + (size_t)arow * D + ks * 32 + kb);
    else { for (int q = 0; q < 8; ++q) t[q] = 0; }
    a[ks] = t;
  }

  int rbase = r0 + (lane >> 4) * 4;

#pragma unroll
  for (int wm = 0; wm < 2; ++wm) {
    const unsigned short* Wb = (wm == 0) ? W1b : W2b;
    const float* bias        = (wm == 0) ? b1 : b2;
    float* Cf                = (wm == 0) ? C1 : C2;
#pragma unroll
    for (int ct = 0; ct < 8; ++ct) {
      int col = ct * 16 + (lane & 15);
      f32x4 acc = {0.f, 0.f, 0.f, 0.f};
#pragma unroll
      for (int ks = 0; ks < 4; ++ks) {
        bf16x8 b = *reinterpret_cast<const bf16x8*>(Wb + (size_t)col * D + ks * 32 + kb);
        acc = __builtin_amdgcn_mfma_f32_16x16x32_bf16(a[ks], b, acc, 0, 0, 0);
      }
      float bc = bias[col];
#pragma unroll
      for (int reg = 0; reg < 4; ++reg) {
        int rr = rbase + reg;
        if (rr < nrows) Cf[(size_t)rr * D + col] = acc[reg] + bc;
      }
    }
  }
}

// ---------------- fallback path (atomic, all f32) ----------------

__global__ __launch_bounds__(256) void k_deg_f(const int* __restrict__ dst,
                                               float* __restrict__ deg, int E) {
  int i = blockIdx.x * 256 + threadIdx.x;
  if (i < E) atomicAdd(&deg[dst[i]], 1.0f);
}

__global__ __launch_bounds__(256) void k_dinv_f(float* __restrict__ deg, int n) {
  int i = blockIdx.x * 256 + threadIdx.x;
  if (i < n) deg[i] = rsqrtf(deg[i] + 1.0f);
}

__global__ __launch_bounds__(256) void k_selfmul(const float* __restrict__ X,
                                                 const float* __restrict__ dinv,
                                                 float* __restrict__ out, int n) {
  int i = blockIdx.x * 256 + threadIdx.x;
  if (i >= n * 32) return;
  int r = i >> 5, c4 = (i & 31) << 2;
  float di = dinv[r];
  float s = di * di;
  float4 h = *(const float4*)(X + (size_t)r * D + c4);
  h.x *= s; h.y *= s; h.z *= s; h.w *= s;
  *(float4*)(out + (size_t)r * D + c4) = h;
}

__global__ __launch_bounds__(256) void k_relumask(float* __restrict__ h,
                                                  const float* __restrict__ mask, int n) {
  int i = blockIdx.x * 256 + threadIdx.x;
  if (i >= n * 32) return;
  float4 v = *(const float4*)(h + (size_t)i * 4);
  float4 m = *(const float4*)(mask + (size_t)i * 4);
  v.x = fmaxf(v.x * m.x, 0.f);
  v.y = fmaxf(v.y * m.y, 0.f);
  v.z = fmaxf(v.z * m.z, 0.f);
  v.w = fmaxf(v.w * m.w, 0.f);
  *(float4*)(h + (size_t)i * 4) = v;
}

__global__ __launch_bounds__(256) void k_aggatomic(const float* __restrict__ X,
                                                   const int* __restrict__ src,
                                                   const int* __restrict__ dst,
                                                   const float* __restrict__ dinv,
                                                   float* __restrict__ out, int E) {
  int gid = blockIdx.x * 256 + threadIdx.x;
  int wave = gid >> 6;
  int lane = threadIdx.x & 63;
  int nw = (gridDim.x * 256) >> 6;
  for (int e = wave; e < E; e += nw) {
    int s = src[e], d = dst[e];
    float nrm = dinv[s] * dinv[d];
    float2 v = ((const float2*)(X + (size_t)s * D))[lane];
    float* op = out + (size_t)d * D + lane * 2;
    atomicAdd(op, v.x * nrm);
    atomicAdd(op + 1, v.y * nrm);
  }
}

__global__ __launch_bounds__(256) void k_addbias(float* __restrict__ C,
                                                 const float* __restrict__ bias, int n) {
  int i = blockIdx.x * 256 + threadIdx.x;
  if (i >= n * 32) return;
  int c4 = (i & 31) << 2;
  float4 v = *(const float4*)(C + (size_t)i * 4);
  float4 b = *(const float4*)(bias + c4);
  v.x += b.x; v.y += b.y; v.z += b.z; v.w += b.w;
  *(float4*)(C + (size_t)i * 4) = v;
}

__global__ __launch_bounds__(256) void k_gemm128(const float* __restrict__ X,
                                                 const float* __restrict__ W,
                                                 const float* __restrict__ bias,
                                                 float* __restrict__ Cf,
                                                 int nrows) {
  __shared__ float Xs[64][132];
  __shared__ float Ws[32][128];

  int tid = threadIdx.x;
  int row0 = blockIdx.x * 64;

  for (int t = tid; t < 2048; t += 256) {
    int r = t >> 5;
    int c4 = (t & 31) << 2;
    int gr = row0 + r;
    float4 v = make_float4(0.f, 0.f, 0.f, 0.f);
    if (gr < nrows) v = *(const float4*)(X + (size_t)gr * D + c4);
    Xs[r][c4 + 0] = v.x; Xs[r][c4 + 1] = v.y;
    Xs[r][c4 + 2] = v.z; Xs[r][c4 + 3] = v.w;
  }

  float acc[4][8];
#pragma unroll
  for (int i = 0; i < 4; ++i)
#pragma unroll
    for (int j = 0; j < 8; ++j) acc[i][j] = 0.f;

  int ty = tid >> 4, tx = tid & 15;
  int r0 = ty << 2, c0 = tx << 3;

  for (int k0 = 0; k0 < 128; k0 += 32) {
    int j = tid >> 1;
    int kkb = (tid & 1) << 4;
    const float4* wp = (const float4*)(W + j * D + k0 + kkb);
    float4 wa = wp[0], wb = wp[1], wc = wp[2], wd = wp[3];

    __syncthreads();
    Ws[kkb +  0][j] = wa.x; Ws[kkb +  1][j] = wa.y; Ws[kkb +  2][j] = wa.z; Ws[kkb +  3][j] = wa.w;
    Ws[kkb +  4][j] = wb.x; Ws[kkb +  5][j] = wb.y; Ws[kkb +  6][j] = wb.z; Ws[kkb +  7][j] = wb.w;
    Ws[kkb +  8][j] = wc.x; Ws[kkb +  9][j] = wc.y; Ws[kkb + 10][j] = wc.z; Ws[kkb + 11][j] = wc.w;
    Ws[kkb + 12][j] = wd.x; Ws[kkb + 13][j] = wd.y; Ws[kkb + 14][j] = wd.z; Ws[kkb + 15][j] = wd.w;
    __syncthreads();

#pragma unroll
    for (int kk = 0; kk < 32; ++kk) {
      float xi[4];
      xi[0] = Xs[r0 + 0][k0 + kk];
      xi[1] = Xs[r0 + 1][k0 + kk];
      xi[2] = Xs[r0 + 2][k0 + kk];
      xi[3] = Xs[r0 + 3][k0 + kk];
      float4 wv0 = *(const float4*)(&Ws[kk][c0]);
      float4 wv1 = *(const float4*)(&Ws[kk][c0 + 4]);
      float wf[8] = {wv0.x, wv0.y, wv0.z, wv0.w, wv1.x, wv1.y, wv1.z, wv1.w};
#pragma unroll
      for (int i = 0; i < 4; ++i)
#pragma unroll
        for (int jj = 0; jj < 8; ++jj) acc[i][jj] += xi[i] * wf[jj];
    }
  }

  float4 bv0 = make_float4(0.f, 0.f, 0.f, 0.f);
  float4 bv1 = make_float4(0.f, 0.f, 0.f, 0.f);
  if (bias) {
    bv0 = *(const float4*)(bias + c0);
    bv1 = *(const float4*)(bias + c0 + 4);
  }

#pragma unroll
  for (int i = 0; i < 4; ++i) {
    int gr = row0 + r0 + i;
    if (gr < nrows) {
      *(float4*)(Cf + (size_t)gr * D + c0) =
          make_float4(acc[i][0] + bv0.x, acc[i][1] + bv0.y,
                      acc[i][2] + bv0.z, acc[i][3] + bv0.w);
      *(float4*)(Cf + (size_t)gr * D + c0 + 4) =
          make_float4(acc[i][4] + bv1.x, acc[i][5] + bv1.y,
                      acc[i][6] + bv1.z, acc[i][7] + bv1.w);
    }
  }
}

// ---------------- launch ----------------

extern "C" void kernel_launch(void* const* d_in, const int* in_sizes, int n_in,
                              void* d_out, int out_size, void* d_ws, size_t ws_size,
                              hipStream_t stream) {
  const float* x    = (const float*)d_in[0];
  const int*   ei   = (const int*)d_in[1];
  const float* mask = (const float*)d_in[2];
  const float* W0   = (const float*)d_in[3];
  const float* b0   = (const float*)d_in[4];
  const float* W1   = (const float*)d_in[5];
  const float* b1   = (const float*)d_in[6];
  const float* W2   = (const float*)d_in[7];
  const float* b2   = (const float*)d_in[8];

  const int N = in_sizes[0] / D;
  const int E = in_sizes[1] / 2;
  const int* srcv = ei;
  const int* dstv = ei + E;

  float* out  = (float*)d_out;
  float* outA = out;                    // x_
  float* outB = out + (size_t)N * D;    // x2

  const size_t featBytes  = (size_t)N * D * sizeof(float);
  const size_t featBytesH = (size_t)N * D * sizeof(short);
  const int gGemm  = (N + 63) / 64;
  const int gEdge  = (E + 255) / 256;
  const int gNode  = (N + 255) / 256;
  const int gWaveN = (N + 3) / 4;
  const int gElem  = (N * 32 + 255) / 256;
  const int nb     = (N + BK_NODES - 1) >> BK_SHIFT;
  const int gBA    = (E + TILE_A - 1) / TILE_A;
  const size_t padBytes = (size_t)nb * CAP * 4;   // packed (aliases gbf)

  auto align256 = [](size_t v) { return (v + 255) & ~(size_t)255; };
  char* w = (char*)d_ws;
  size_t off = 0;
  int*   bcnt      = (int*)(w + off);   off = align256(off + (NBMAX + 1) * 4);
  int*   gcur      = bcnt + NBMAX;      // one extra int, zeroed with bcnt
  int*   rowBeg    = (int*)(w + off);   off = align256(off + (size_t)N * 4);
  int*   rowEnd    = (int*)(w + off);   off = align256(off + (size_t)N * 4);
  float* dinv      = (float*)(w + off); off = align256(off + (size_t)N * 4);
  int*   srcSorted = (int*)(w + off);   off = align256(off + (size_t)E * 4);
  unsigned short* Wb = (unsigned short*)(w + off); off = align256(off + 3 * 16384 * 2);
  unsigned* h0bf   = (unsigned*)(w + off); off = align256(off + featBytesH);
  unsigned* hbf    = (unsigned*)(w + off); off = align256(off + featBytesH);
  unsigned* gbf    = (unsigned*)(w + off);
  size_t offA = off + featBytesH;
  size_t offB = off + padBytes;
  off = align256(offA > offB ? offA : offB);
  int*   packed    = (int*)gbf;         // aliases gbf (consumed before written)
  size_t need = off;

  if (ws_size >= need && N <= 65536 && nb <= NBMAX &&
      (E / nb) + 1024 <= CAP) {
    // ---- CSR build (2 kernels + tiny memset); bucketA also converts W ----
    hipMemsetAsync(bcnt, 0, (size_t)(NBMAX + 1) * sizeof(int), stream);
    k_bucketA<<<gBA, 512, 0, stream>>>(srcv, dstv, bcnt, packed,
                                       W0, W1, W2, Wb, E, nb);
    k_bucketB2<<<nb, 512, 0, stream>>>(packed, bcnt, gcur, srcSorted,
                                       rowBeg, rowEnd, dinv, N);

    // t0 = bf16(dinv * (x @ W0^T))
    k_gemm_mfma<false, true><<<gGemm, 256, 0, stream>>>(
        x, Wb, nullptr, dinv, nullptr, (unsigned short*)h0bf, N);
    // t1 = bf16(dinv * relu((agg + b0) * mask))
    k_aggb<1><<<gWaveN, 256, 0, stream>>>(h0bf, srcSorted, rowBeg, rowEnd,
                                          dinv, b0, mask, hbf, N);
    // g = bf16(agg)
    k_aggb<2><<<gWaveN, 256, 0, stream>>>(hbf, srcSorted, rowBeg, rowEnd,
                                          dinv, nullptr, nullptr, gbf, N);
    // x_ = g @ W1^T + b1 ; x2 = g @ W2^T + b2 (fused)
    k_gemm_mfma2<<<gGemm, 256, 0, stream>>>(
        (const unsigned short*)gbf, Wb + 16384, Wb + 32768, b1, b2,
        outA, outB, N);
  } else {
    // ---- atomic fallback (commuted, 2 aggs, all f32) ----
    float* fdinv = (float*)(w);
    float* fA    = (float*)(w + 0x40000);
    float* fB    = (float*)((char*)fA + featBytes);
    hipMemsetAsync(fdinv, 0, (size_t)N * sizeof(float), stream);
    k_deg_f<<<gEdge, 256, 0, stream>>>(dstv, fdinv, E);
    k_dinv_f<<<gNode, 256, 0, stream>>>(fdinv, N);
    k_gemm128<<<gGemm, 256, 0, stream>>>(x, W0, nullptr, fB, N);
    k_selfmul<<<gElem, 256, 0, stream>>>(fB, fdinv, fA, N);
    k_aggatomic<<<4096, 256, 0, stream>>>(fB, srcv, dstv, fdinv, fA, E);
    k_addbias<<<gElem, 256, 0, stream>>>(fA, b0, N);
    k_relumask<<<gElem, 256, 0, stream>>>(fA, mask, N);
    k_selfmul<<<gElem, 256, 0, stream>>>(fA, fdinv, fB, N);
    k_aggatomic<<<4096, 256, 0, stream>>>(fA, srcv, dstv, fdinv, fB, E);
    k_gemm128<<<gGemm, 256, 0, stream>>>(fB, W1, b1, outA, N);
    k_gemm128<<<gGemm, 256, 0, stream>>>(fB, W2, b2, outB, N);
  }
}